// Round 12
// baseline (1506.434 us; speedup 1.0000x reference)
//
#include <hip/hip_runtime.h>
#include <cstdint>
#include <cstddef>

typedef __attribute__((ext_vector_type(8))) short short8;
typedef __attribute__((ext_vector_type(4))) float f32x4;
typedef __attribute__((ext_vector_type(4))) unsigned short us4;

#define DEVINL static __device__ __forceinline__
#define AS1 __attribute__((address_space(1)))
#define AS3 __attribute__((address_space(3)))

DEVINL float bf2f(unsigned short u){
  union { unsigned uu; float f; } v; v.uu = ((unsigned)u) << 16; return v.f;
}
DEVINL unsigned short f2bf(float f){
  unsigned u = __float_as_uint(f);
  u += 0x7fffu + ((u >> 16) & 1u);
  return (unsigned short)(u >> 16);
}

// strict total order: value desc, index asc (JAX top_k tie semantics)
DEVINL bool tk_better(float av, int ai, float bv, int bi){
  return (av > bv) || (av == bv && ai < bi);
}
DEVINL void tk_cmpex(float& va, int& ia, float& vb, int& ib){
  if (!tk_better(va, ia, vb, ib)){
    float tv = va; va = vb; vb = tv;
    int t = ia; ia = ib; ib = t;
  }
}
DEVINL void tk_sort4(float* v, int* id){
  tk_cmpex(v[0], id[0], v[1], id[1]);
  tk_cmpex(v[2], id[2], v[3], id[3]);
  tk_cmpex(v[0], id[0], v[2], id[2]);
  tk_cmpex(v[1], id[1], v[3], id[3]);
  tk_cmpex(v[1], id[1], v[2], id[2]);
}
DEVINL void tk_bmerge(float* v, int* id, const float* pv, const int* pi){
  #pragma unroll
  for (int i = 0; i < 4; ++i){
    bool ta = tk_better(v[i], id[i], pv[3 - i], pi[3 - i]);
    v[i]  = ta ? v[i]  : pv[3 - i];
    id[i] = ta ? id[i] : pi[3 - i];
  }
  tk_cmpex(v[0], id[0], v[2], id[2]);
  tk_cmpex(v[1], id[1], v[3], id[3]);
  tk_cmpex(v[0], id[0], v[1], id[1]);
  tk_cmpex(v[2], id[2], v[3], id[3]);
}

__global__ void k_diag(float* out, float v){ out[0] = v; }

// ---------------- cast f32 -> bf16 ----------------
__global__ __launch_bounds__(256) void k_cast_bf16(const float* __restrict__ x,
                                                   unsigned short* __restrict__ y, int n4){
  int stride = gridDim.x * blockDim.x;
  for (int i = blockIdx.x * blockDim.x + threadIdx.x; i < n4; i += stride){
    float4 v = ((const float4*)x)[i];
    us4 o; o[0] = f2bf(v.x); o[1] = f2bf(v.y); o[2] = f2bf(v.z); o[3] = f2bf(v.w);
    ((us4*)y)[i] = o;
  }
}

// ---------------- transpose-cast f32 [R][C] -> bf16 [C][R] ----------------
__global__ __launch_bounds__(256) void k_tcast(const float* __restrict__ in,
    unsigned short* __restrict__ outT, int R, int C){
  __shared__ float t[32][33];
  const int bc = blockIdx.x * 32, br = blockIdx.y * 32;
  const int lx = threadIdx.x & 31, ly = threadIdx.x >> 5;
  #pragma unroll
  for (int i = 0; i < 32; i += 8)
    t[ly + i][lx] = in[(size_t)(br + ly + i) * C + bc + lx];
  __syncthreads();
  #pragma unroll
  for (int i = 0; i < 32; i += 8)
    outT[(size_t)(bc + ly + i) * R + br + lx] = f2bf(t[lx][ly + i]);
}

// ---------------- bias precompute: bc[j] = sum_m w1[j,m]*outb[m&1023] + b1[j] ----------------
__global__ __launch_bounds__(256) void k_bias_pre(const float* __restrict__ w1,
    const float* __restrict__ outb, const float* __restrict__ b1, float* __restrict__ bc){
  int wave = threadIdx.x >> 6, lane = threadIdx.x & 63;
  int j = blockIdx.x * 4 + wave;
  float s = 0.f;
  for (int m = lane; m < 2048; m += 64)
    s += w1[(size_t)j * 2048 + m] * outb[m & 1023];
  #pragma unroll
  for (int m = 32; m >= 1; m >>= 1) s += __shfl_xor(s, m);
  if (lane == 0) bc[j] = s + b1[j];
}

// ---------------- bias precompute: bc[n] = sum_m wih[n,m]*b2[m] + bih[n] ----------------
__global__ __launch_bounds__(256) void k_bias_gi(const float* __restrict__ wih,
    const float* __restrict__ b2, const float* __restrict__ bih, float* __restrict__ bc){
  int wave = threadIdx.x >> 6, lane = threadIdx.x & 63;
  int n = blockIdx.x * 4 + wave;
  float s = 0.f;
  for (int m = lane; m < 1024; m += 64)
    s += wih[(size_t)n * 1024 + m] * b2[m];
  #pragma unroll
  for (int m = 32; m >= 1; m >>= 1) s += __shfl_xor(s, m);
  if (lane == 0) bc[n] = s + bih[n];
}

// ---------------- per-key scale/bias ----------------
__global__ __launch_bounds__(256) void k_prep_keys(const float* __restrict__ keys,
    const float* __restrict__ last_access, const float* __restrict__ importance,
    const float* __restrict__ consolid, const float* __restrict__ emo,
    const float* __restrict__ active, float* __restrict__ ascale, float* __restrict__ bbias){
  int wave = threadIdx.x >> 6, lane = threadIdx.x & 63;
  int n = blockIdx.x * 4 + wave;
  const float* kr = keys + (size_t)n * 1024;
  float s = 0.f;
  #pragma unroll
  for (int j = 0; j < 4; ++j){
    float4 v = ((const float4*)kr)[j * 64 + lane];
    s += v.x*v.x + v.y*v.y + v.z*v.z + v.w*v.w;
  }
  #pragma unroll
  for (int m = 32; m >= 1; m >>= 1) s += __shfl_xor(s, m);
  if (lane == 0){
    float norm = fmaxf(sqrtf(s), 1e-8f);
    float forget = expf(-0.001f * (100.0f - last_access[n]));
    float bo = 0.f;
    #pragma unroll
    for (int j = 0; j < 8; ++j) bo += emo[n * 8 + j];
    bo = bo * 0.1f + importance[n] * 0.2f + log1pf(consolid[n]) * 0.1f;
    float a = active[n];
    ascale[n] = forget * a / norm;
    bbias[n]  = bo * a;
  }
}

// ---------------- per-query inverse norm ----------------
__global__ __launch_bounds__(256) void k_qnorm(const float* __restrict__ q, float* __restrict__ qinv){
  int wave = threadIdx.x >> 6, lane = threadIdx.x & 63;
  int b = blockIdx.x * 4 + wave;
  const float* qr = q + (size_t)b * 1024;
  float s = 0.f;
  #pragma unroll
  for (int j = 0; j < 4; ++j){
    float4 v = ((const float4*)qr)[j * 64 + lane];
    s += v.x*v.x + v.y*v.y + v.z*v.z + v.w*v.w;
  }
  #pragma unroll
  for (int m = 32; m >= 1; m >>= 1) s += __shfl_xor(s, m);
  if (lane == 0) qinv[b] = 1.0f / fmaxf(sqrtf(s), 1e-8f);
}

// ---------------- split f32 -> concat-K bf16 panels: h -> offH1 & offH2, l -> offL ----------------
// D row stride 3072. dot(QX,KX) over K=3072 == Qh*Kh + Ql*Kh + Qh*Kl (split-bf16 product).
__global__ __launch_bounds__(256) void k_split3(const float* __restrict__ X,
    const float* __restrict__ rscale, unsigned short* __restrict__ D,
    int offH1, int offH2, int offL){
  const int row = blockIdx.x;
  const float sc = rscale ? rscale[row] : 1.0f;
  const int d = threadIdx.x * 4;
  float4 v = *(const float4*)(X + (size_t)row * 1024 + d);
  float xs[4] = {v.x * sc, v.y * sc, v.z * sc, v.w * sc};
  us4 h, l;
  #pragma unroll
  for (int j = 0; j < 4; ++j){
    unsigned short hb = f2bf(xs[j]);
    h[j] = hb;
    l[j] = f2bf(xs[j] - bf2f(hb));
  }
  unsigned short* base = D + (size_t)row * 3072;
  *(us4*)(base + offH1 + d) = h;
  *(us4*)(base + offH2 + d) = h;
  *(us4*)(base + offL  + d) = l;
}

// ---------------- scores GEMM, 8-phase 256x256 skeleton (R9-verified) + fused top-4 epilogue ----
// QX [8192][3072], KX [4096][3072]; score = dot*ascale[col] + bbias[col].
// Grid (32,16) = 512 blocks = 2 exact CU-waves. Candidates: 256/row (16 tN x 4 wqc x 4).
__global__ __launch_bounds__(512, 2) void k_scores8p(const unsigned short* __restrict__ QX,
    const unsigned short* __restrict__ KX, const float* __restrict__ ascale,
    const float* __restrict__ bbias, float* __restrict__ candV, int* __restrict__ candI){
  __shared__ __align__(16) unsigned short lds[65536];
  const int tid = threadIdx.x;
  const int wave = tid >> 6, lane = tid & 63;
  const int wqr = wave >> 2, wqc = wave & 3;
  const int lrow = lane & 15, lkk = lane >> 4;
  const int K = 3072;

  const int nwg = gridDim.x * gridDim.y;
  int lin = blockIdx.y * gridDim.x + blockIdx.x;
  int cpx = nwg >> 3;
  int swz = (lin & 7) * cpx + (lin >> 3);
  const int nM = 32;
  const int tM = swz % nM, tN = swz / nM;

  const unsigned short* Abase = QX + (size_t)tM * 256 * K;
  const unsigned short* Wbase = KX + (size_t)tN * 256 * K;

  f32x4 a00[4][2] = {}, a01[4][2] = {}, a11[4][2] = {}, a10[4][2] = {};
  short8 af[4][2], bf[2][2];
  const int ntiles = K >> 6;   // 48

  auto stage = [&](int op, int slot, int half, int tile){
    if (tile >= ntiles) return;
    const unsigned short* G = op ? Wbase : Abase;
    const int k0 = tile * 64, hr = half * 128;
    const int base = op * 32768 + slot * 16384 + half * 8192;
    #pragma unroll
    for (int l = 0; l < 2; ++l){
      int p = l * 512 + tid;
      int row = p >> 3, c = (p & 7) ^ (row & 7);
      int dstc = l * 512 + wave * 64;
      __builtin_amdgcn_global_load_lds(
          (const AS1 void*)(G + (size_t)(hr + row) * K + k0 + c * 8),
          (AS3 void*)(lds + base + dstc * 8), 16, 0, 0);
    }
  };
  auto ldA = [&](int slot, int half){
    const int base = slot * 16384 + half * 8192;
    #pragma unroll
    for (int mi = 0; mi < 4; ++mi)
      #pragma unroll
      for (int kk = 0; kk < 2; ++kk){
        int row = wqr * 64 + mi * 16 + lrow;
        int c = kk * 4 + lkk;
        af[mi][kk] = *(const short8*)(lds + base + (row * 8 + (c ^ (row & 7))) * 8);
      }
  };
  auto ldB = [&](int slot, int half){
    const int base = 32768 + slot * 16384 + half * 8192;
    #pragma unroll
    for (int ni = 0; ni < 2; ++ni)
      #pragma unroll
      for (int kk = 0; kk < 2; ++kk){
        int row = wqc * 32 + ni * 16 + lrow;
        int c = kk * 4 + lkk;
        bf[ni][kk] = *(const short8*)(lds + base + (row * 8 + (c ^ (row & 7))) * 8);
      }
  };
  auto mfma16 = [&](f32x4 (&acc)[4][2]){
    __builtin_amdgcn_s_setprio(1);
    #pragma unroll
    for (int mi = 0; mi < 4; ++mi)
      #pragma unroll
      for (int ni = 0; ni < 2; ++ni)
        #pragma unroll
        for (int kk = 0; kk < 2; ++kk)
          acc[mi][ni] = __builtin_amdgcn_mfma_f32_16x16x32_bf16(af[mi][kk], bf[ni][kk], acc[mi][ni], 0, 0, 0);
    __builtin_amdgcn_s_setprio(0);
  };
  auto SB = [&](){
    __builtin_amdgcn_sched_barrier(0);
    __builtin_amdgcn_s_barrier();
    __builtin_amdgcn_sched_barrier(0);
  };

  stage(0,0,0, 0); stage(1,0,0, 0); stage(1,0,1, 0); stage(0,0,1, 0);
  stage(0,1,0, 1); stage(1,1,1, 1);
  __builtin_amdgcn_sched_barrier(0);
  asm volatile("s_waitcnt vmcnt(4)" ::: "memory");
  __builtin_amdgcn_s_barrier();
  __builtin_amdgcn_sched_barrier(0);

  for (int j = 0; j < (ntiles >> 1); ++j){
    const int t0 = 2 * j;
    ldA(0,0); ldB(0,0); stage(0,1,1, t0+1);
    SB(); mfma16(a00); SB();
    ldB(0,1); stage(1,1,0, t0+1);
    SB(); mfma16(a01); SB();
    ldA(0,1); stage(0,0,0, t0+2);
    SB(); mfma16(a11); SB();
    ldB(0,0); stage(1,0,1, t0+2);
    SB(); mfma16(a10);
    __builtin_amdgcn_sched_barrier(0);
    if (t0 + 2 < ntiles) asm volatile("s_waitcnt vmcnt(4)" ::: "memory");
    else                 asm volatile("s_waitcnt vmcnt(0)" ::: "memory");
    __builtin_amdgcn_s_barrier();
    __builtin_amdgcn_sched_barrier(0);
    ldA(1,0); ldB(1,0); stage(0,0,1, t0+2);
    SB(); mfma16(a00); SB();
    ldB(1,1); stage(1,0,0, t0+2);
    SB(); mfma16(a01); SB();
    ldA(1,1); stage(0,1,0, t0+3);
    SB(); mfma16(a11); SB();
    ldB(1,0); stage(1,1,1, t0+3);
    SB(); mfma16(a10);
    __builtin_amdgcn_sched_barrier(0);
    asm volatile("s_waitcnt vmcnt(4)" ::: "memory");
    __builtin_amdgcn_s_barrier();
    __builtin_amdgcn_sched_barrier(0);
  }

  // ---- fused top-4 epilogue ----
  const int lc = lane & 15, lgrp = lane >> 4;
  float as_[2][2], bb_[2][2]; int cid[2][2];
  #pragma unroll
  for (int NH = 0; NH < 2; ++NH)
    #pragma unroll
    for (int ni = 0; ni < 2; ++ni){
      int col = tN * 256 + NH * 128 + wqc * 32 + ni * 16 + lc;
      cid[NH][ni] = col;
      as_[NH][ni] = ascale[col];
      bb_[NH][ni] = bbias[col];
    }
  auto epi = [&](f32x4 (&n0)[4][2], f32x4 (&n1)[4][2], int MH){
    #pragma unroll
    for (int mi = 0; mi < 4; ++mi){
      #pragma unroll
      for (int r = 0; r < 4; ++r){
        float v[4]; int id[4];
        v[0] = n0[mi][0][r] * as_[0][0] + bb_[0][0]; id[0] = cid[0][0];
        v[1] = n0[mi][1][r] * as_[0][1] + bb_[0][1]; id[1] = cid[0][1];
        v[2] = n1[mi][0][r] * as_[1][0] + bb_[1][0]; id[2] = cid[1][0];
        v[3] = n1[mi][1][r] * as_[1][1] + bb_[1][1]; id[3] = cid[1][1];
        tk_sort4(v, id);
        #pragma unroll
        for (int mask = 1; mask <= 8; mask <<= 1){
          float pv[4]; int pi_[4];
          #pragma unroll
          for (int jj = 0; jj < 4; ++jj){
            pv[jj]  = __shfl_xor(v[jj], mask);
            pi_[jj] = __shfl_xor(id[jj], mask);
          }
          tk_bmerge(v, id, pv, pi_);
        }
        if (lc == 0){
          int row = tM * 256 + MH * 128 + wqr * 64 + mi * 16 + lgrp * 4 + r;
          size_t cb = (size_t)row * 256 + tN * 16 + wqc * 4;
          #pragma unroll
          for (int jj = 0; jj < 4; ++jj){ candV[cb + jj] = v[jj]; candI[cb + jj] = id[jj]; }
        }
      }
    }
  };
  epi(a00, a01, 0);
  epi(a10, a11, 1);
}

// ---------------- merge 256 candidates/row -> top-4 + softmax + V gather ----------------
__global__ __launch_bounds__(256) void k_topk_merge(const float* __restrict__ candV,
    const int* __restrict__ candI, const float* __restrict__ V,
    unsigned short* __restrict__ schema_bf){
  const int row = blockIdx.x, tid = threadIdx.x;
  const int wave = tid >> 6, lane = tid & 63;
  float v[4]; int id[4];
  v[0] = candV[(size_t)row * 256 + tid];
  id[0] = candI[(size_t)row * 256 + tid];
  #pragma unroll
  for (int j = 1; j < 4; ++j){ v[j] = -3.4e38f; id[j] = 0x7fffffff; }
  #pragma unroll
  for (int mask = 1; mask <= 32; mask <<= 1){
    float pv[4]; int pi_[4];
    #pragma unroll
    for (int j = 0; j < 4; ++j){
      pv[j]  = __shfl_xor(v[j], mask);
      pi_[j] = __shfl_xor(id[j], mask);
    }
    tk_bmerge(v, id, pv, pi_);
  }
  __shared__ float wv[4][4]; __shared__ int wi[4][4];
  if (lane == 0){
    #pragma unroll
    for (int j = 0; j < 4; ++j){ wv[wave][j] = v[j]; wi[wave][j] = id[j]; }
  }
  __syncthreads();
  __shared__ float w_sh[4]; __shared__ int i_sh[4];
  if (tid == 0){
    float fv[4]; int fi[4];
    #pragma unroll
    for (int j = 0; j < 4; ++j){ fv[j] = wv[0][j]; fi[j] = wi[0][j]; }
    #pragma unroll
    for (int w = 1; w < 4; ++w){
      float pv[4]; int pi_[4];
      #pragma unroll
      for (int j = 0; j < 4; ++j){ pv[j] = wv[w][j]; pi_[j] = wi[w][j]; }
      tk_bmerge(fv, fi, pv, pi_);
    }
    float m = fv[0];
    float e0 = expf(fv[0] - m), e1 = expf(fv[1] - m), e2 = expf(fv[2] - m), e3 = expf(fv[3] - m);
    float inv = 1.f / (e0 + e1 + e2 + e3);
    w_sh[0] = e0 * inv; w_sh[1] = e1 * inv; w_sh[2] = e2 * inv; w_sh[3] = e3 * inv;
    i_sh[0] = fi[0]; i_sh[1] = fi[1]; i_sh[2] = fi[2]; i_sh[3] = fi[3];
  }
  __syncthreads();
  float w0 = w_sh[0], w1 = w_sh[1], w2 = w_sh[2], w3 = w_sh[3];
  const float* v0 = V + (size_t)i_sh[0] * 1024;
  const float* v1 = V + (size_t)i_sh[1] * 1024;
  const float* v2 = V + (size_t)i_sh[2] * 1024;
  const float* v3 = V + (size_t)i_sh[3] * 1024;
  int d = tid * 4;
  float4 a = *(const float4*)(v0 + d);
  float4 b4 = *(const float4*)(v1 + d);
  float4 c = *(const float4*)(v2 + d);
  float4 e = *(const float4*)(v3 + d);
  us4 o;
  o[0] = f2bf(w0*a.x + w1*b4.x + w2*c.x + w3*e.x);
  o[1] = f2bf(w0*a.y + w1*b4.y + w2*c.y + w3*e.y);
  o[2] = f2bf(w0*a.z + w1*b4.z + w2*c.z + w3*e.z);
  o[3] = f2bf(w0*a.w + w1*b4.w + w2*c.w + w3*e.w);
  *(us4*)(schema_bf + (size_t)row * 1024 + d) = o;
}

// ---------------- state init ----------------
__global__ __launch_bounds__(256) void k_initstate(const float* __restrict__ wm,
    float* __restrict__ st, unsigned short* __restrict__ stbf){
  size_t i = ((size_t)blockIdx.x * 256 + threadIdx.x) * 4;
  float4 v = *(const float4*)(wm + i);
  *(float4*)(st + i) = v;
  us4 o; o[0] = f2bf(v.x); o[1] = f2bf(v.y); o[2] = f2bf(v.z); o[3] = f2bf(v.w);
  *(us4*)(stbf + i) = o;
}

// ---------------- 128x128 bf16 MFMA GEMM ----------------
template<int OUT_BF16>
__global__ __launch_bounds__(256) void k_gemm(const unsigned short* __restrict__ A,
    const unsigned short* __restrict__ W, const float* __restrict__ bias,
    void* __restrict__ C, int M, int N, int K, int lda, int ldc){
  __shared__ __align__(16) unsigned short As[128 * 32];
  __shared__ __align__(16) unsigned short Ws[128 * 32];
  const int tid = threadIdx.x;
  const int wave = tid >> 6, lane = tid & 63;
  const int tM = blockIdx.x, tN = blockIdx.y;
  const int wm_ = wave >> 1, wn_ = wave & 1;
  f32x4 acc[4][4] = {};
  const unsigned short* Abase = A + (size_t)tM * 128 * lda;
  const unsigned short* Wbase = W + (size_t)tN * 128 * K;
  const int lrow = lane & 15, lk = (lane >> 4) * 8;
  for (int k0 = 0; k0 < K; k0 += 32){
    __syncthreads();
    #pragma unroll
    for (int j = 0; j < 2; ++j){
      int c = wave * 128 + j * 64 + lane;
      int row = c >> 2, cp = c & 3;
      const unsigned short* ga = Abase + (size_t)row * lda + k0 + cp * 8;
      const unsigned short* gw = Wbase + (size_t)row * K + k0 + cp * 8;
      __builtin_amdgcn_global_load_lds((const AS1 void*)ga, (AS3 void*)(As + (wave * 2 + j) * 512), 16, 0, 0);
      __builtin_amdgcn_global_load_lds((const AS1 void*)gw, (AS3 void*)(Ws + (wave * 2 + j) * 512), 16, 0, 0);
    }
    __syncthreads();
    short8 af[4], bfr[4];
    #pragma unroll
    for (int mi = 0; mi < 4; ++mi)
      af[mi] = *(const short8*)(As + (wm_ * 64 + mi * 16 + lrow) * 32 + lk);
    #pragma unroll
    for (int ni = 0; ni < 4; ++ni)
      bfr[ni] = *(const short8*)(Ws + (wn_ * 64 + ni * 16 + lrow) * 32 + lk);
    #pragma unroll
    for (int mi = 0; mi < 4; ++mi)
      #pragma unroll
      for (int ni = 0; ni < 4; ++ni)
        acc[mi][ni] = __builtin_amdgcn_mfma_f32_16x16x32_bf16(af[mi], bfr[ni], acc[mi][ni], 0, 0, 0);
  }
  const int lc = lane & 15, lr = (lane >> 4) * 4;
  #pragma unroll
  for (int ni = 0; ni < 4; ++ni){
    int col = tN * 128 + wn_ * 64 + ni * 16 + lc;
    float bb = bias ? bias[col] : 0.f;
    #pragma unroll
    for (int mi = 0; mi < 4; ++mi){
      int rowb = tM * 128 + wm_ * 64 + mi * 16 + lr;
      #pragma unroll
      for (int r = 0; r < 4; ++r){
        float vv = acc[mi][ni][r] + bb;
        size_t off = (size_t)(rowb + r) * ldc + col;
        if (OUT_BF16) ((unsigned short*)C)[off] = f2bf(vv);
        else ((float*)C)[off] = vv;
      }
    }
  }
}

// ---------------- 256x256 8-phase bf16 MFMA GEMM (R9 verified schedule) ----------------
template<int OUT_BF16>
__global__ __launch_bounds__(512, 2) void k_gemm8p(const unsigned short* __restrict__ A,
    const unsigned short* __restrict__ W, const float* __restrict__ bias,
    void* __restrict__ C, int M, int N, int K, int lda, int ldc){
  __shared__ __align__(16) unsigned short lds[65536];
  const int tid = threadIdx.x;
  const int wave = tid >> 6, lane = tid & 63;
  const int wqr = wave >> 2, wqc = wave & 3;
  const int lrow = lane & 15, lkk = lane >> 4;

  const int nwg = gridDim.x * gridDim.y;
  int lin = blockIdx.y * gridDim.x + blockIdx.x;
  int cpx = nwg >> 3;
  int swz = (lin & 7) * cpx + (lin >> 3);
  const int nM = M >> 8;
  const int tM = swz % nM, tN = swz / nM;

  const unsigned short* Abase = A + (size_t)tM * 256 * lda;
  const unsigned short* Wbase = W + (size_t)tN * 256 * K;

  f32x4 a00[4][2] = {}, a01[4][2] = {}, a11[4][2] = {}, a10[4][2] = {};
  short8 af[4][2], bf[2][2];
  const int ntiles = K >> 6;

  auto stage = [&](int op, int slot, int half, int tile){
    if (tile >= ntiles) return;
    const unsigned short* G = op ? Wbase : Abase;
    const int rs = op ? K : lda;
    const int k0 = tile * 64, hr = half * 128;
    const int base = op * 32768 + slot * 16384 + half * 8192;
    #pragma unroll
    for (int l = 0; l < 2; ++l){
      int p = l * 512 + tid;
      int row = p >> 3, c = (p & 7) ^ (row & 7);
      int dstc = l * 512 + wave * 64;
      __builtin_amdgcn_global_load_lds(
          (const AS1 void*)(G + (size_t)(hr + row) * rs + k0 + c * 8),
          (AS3 void*)(lds + base + dstc * 8), 16, 0, 0);
    }
  };
  auto ldA = [&](int slot, int half){
    const int base = slot * 16384 + half * 8192;
    #pragma unroll
    for (int mi = 0; mi < 4; ++mi)
      #pragma unroll
      for (int kk = 0; kk < 2; ++kk){
        int row = wqr * 64 + mi * 16 + lrow;
        int c = kk * 4 + lkk;
        af[mi][kk] = *(const short8*)(lds + base + (row * 8 + (c ^ (row & 7))) * 8);
      }
  };
  auto ldB = [&](int slot, int half){
    const int base = 32768 + slot * 16384 + half * 8192;
    #pragma unroll
    for (int ni = 0; ni < 2; ++ni)
      #pragma unroll
      for (int kk = 0; kk < 2; ++kk){
        int row = wqc * 32 + ni * 16 + lrow;
        int c = kk * 4 + lkk;
        bf[ni][kk] = *(const short8*)(lds + base + (row * 8 + (c ^ (row & 7))) * 8);
      }
  };
  auto mfma16 = [&](f32x4 (&acc)[4][2]){
    __builtin_amdgcn_s_setprio(1);
    #pragma unroll
    for (int mi = 0; mi < 4; ++mi)
      #pragma unroll
      for (int ni = 0; ni < 2; ++ni)
        #pragma unroll
        for (int kk = 0; kk < 2; ++kk)
          acc[mi][ni] = __builtin_amdgcn_mfma_f32_16x16x32_bf16(af[mi][kk], bf[ni][kk], acc[mi][ni], 0, 0, 0);
    __builtin_amdgcn_s_setprio(0);
  };
  auto SB = [&](){
    __builtin_amdgcn_sched_barrier(0);
    __builtin_amdgcn_s_barrier();
    __builtin_amdgcn_sched_barrier(0);
  };

  stage(0,0,0, 0); stage(1,0,0, 0); stage(1,0,1, 0); stage(0,0,1, 0);
  stage(0,1,0, 1); stage(1,1,1, 1);
  __builtin_amdgcn_sched_barrier(0);
  asm volatile("s_waitcnt vmcnt(4)" ::: "memory");
  __builtin_amdgcn_s_barrier();
  __builtin_amdgcn_sched_barrier(0);

  for (int j = 0; j < (ntiles >> 1); ++j){
    const int t0 = 2 * j;
    ldA(0,0); ldB(0,0); stage(0,1,1, t0+1);
    SB(); mfma16(a00); SB();
    ldB(0,1); stage(1,1,0, t0+1);
    SB(); mfma16(a01); SB();
    ldA(0,1); stage(0,0,0, t0+2);
    SB(); mfma16(a11); SB();
    ldB(0,0); stage(1,0,1, t0+2);
    SB(); mfma16(a10);
    __builtin_amdgcn_sched_barrier(0);
    if (t0 + 2 < ntiles) asm volatile("s_waitcnt vmcnt(4)" ::: "memory");
    else                 asm volatile("s_waitcnt vmcnt(0)" ::: "memory");
    __builtin_amdgcn_s_barrier();
    __builtin_amdgcn_sched_barrier(0);
    ldA(1,0); ldB(1,0); stage(0,0,1, t0+2);
    SB(); mfma16(a00); SB();
    ldB(1,1); stage(1,0,0, t0+2);
    SB(); mfma16(a01); SB();
    ldA(1,1); stage(0,1,0, t0+3);
    SB(); mfma16(a11); SB();
    ldB(1,0); stage(1,1,1, t0+3);
    SB(); mfma16(a10);
    __builtin_amdgcn_sched_barrier(0);
    asm volatile("s_waitcnt vmcnt(4)" ::: "memory");
    __builtin_amdgcn_s_barrier();
    __builtin_amdgcn_sched_barrier(0);
  }

  const int lc = lane & 15, lr = (lane >> 4) * 4;
  auto wout = [&](f32x4 (&acc)[4][2], int MH, int NH){
    #pragma unroll
    for (int ni = 0; ni < 2; ++ni){
      int col = tN * 256 + NH * 128 + wqc * 32 + ni * 16 + lc;
      float bb = bias ? bias[col] : 0.f;
      #pragma unroll
      for (int mi = 0; mi < 4; ++mi){
        int rowb = tM * 256 + MH * 128 + wqr * 64 + mi * 16 + lr;
        #pragma unroll
        for (int r = 0; r < 4; ++r){
          float vv = acc[mi][ni][r] + bb;
          size_t off = (size_t)(rowb + r) * ldc + col;
          if (OUT_BF16) ((unsigned short*)C)[off] = f2bf(vv);
          else ((float*)C)[off] = vv;
        }
      }
    }
  };
  wout(a00, 0, 0); wout(a01, 0, 1); wout(a11, 1, 1); wout(a10, 1, 0);
}

// ---------------- 2-token MHA, in-place into qgh cols 0..2047 ----------------
__global__ __launch_bounds__(256) void k_attn(unsigned short* qgh,
    const unsigned short* __restrict__ qkvM){
  const int b = blockIdx.x, tid = threadIdx.x;
  const int l = tid & 31;
  const int e = (tid >> 5) * 128 + l * 4;
  unsigned short* ps = qgh + (size_t)b * 6144;
  const unsigned short* pm = qkvM + (size_t)b * 3072;
  float q0[4], kk0[4], v0[4], q1[4], kk1[4], v1[4];
  us4 t;
  t = *(const us4*)(ps + e);        for (int j = 0; j < 4; ++j) q0[j]  = bf2f(t[j]);
  t = *(const us4*)(ps + 1024 + e); for (int j = 0; j < 4; ++j) kk0[j] = bf2f(t[j]);
  t = *(const us4*)(ps + 2048 + e); for (int j = 0; j < 4; ++j) v0[j]  = bf2f(t[j]);
  t = *(const us4*)(pm + e);        for (int j = 0; j < 4; ++j) q1[j]  = bf2f(t[j]);
  t = *(const us4*)(pm + 1024 + e); for (int j = 0; j < 4; ++j) kk1[j] = bf2f(t[j]);
  t = *(const us4*)(pm + 2048 + e); for (int j = 0; j < 4; ++j) v1[j]  = bf2f(t[j]);
  float s00 = 0.f, s01 = 0.f, s10 = 0.f, s11 = 0.f;
  #pragma unroll
  for (int j = 0; j < 4; ++j){
    s00 += q0[j] * kk0[j]; s01 += q0[j] * kk1[j];
    s10 += q1[j] * kk0[j]; s11 += q1[j] * kk1[j];
  }
  #pragma unroll
  for (int m = 16; m >= 1; m >>= 1){
    s00 += __shfl_xor(s00, m); s01 += __shfl_xor(s01, m);
    s10 += __shfl_xor(s10, m); s11 += __shfl_xor(s11, m);
  }
  const float sc = 0.08838834764831845f; // 1/sqrt(128)
  s00 *= sc; s01 *= sc; s10 *= sc; s11 *= sc;
  float m0 = fmaxf(s00, s01), m1 = fmaxf(s10, s11);
  float e00 = expf(s00 - m0), e01 = expf(s01 - m0);
  float e10 = expf(s10 - m1), e11 = expf(s11 - m1);
  float i0 = 1.f / (e00 + e01), i1 = 1.f / (e10 + e11);
  float w00 = e00 * i0, w01 = e01 * i0, w10 = e10 * i1, w11 = e11 * i1;
  us4 o0, o1;
  #pragma unroll
  for (int j = 0; j < 4; ++j){
    o0[j] = f2bf(w00 * v0[j] + w01 * v1[j]);
    o1[j] = f2bf(w10 * v0[j] + w11 * v1[j]);
  }
  *(us4*)(ps + e)        = o0;
  *(us4*)(ps + 1024 + e) = o1;
}

// ---------------- row LayerNorm + ReLU -> bf16 (f32 or bf16 input) ----------------
template<int IN_BF16>
__global__ __launch_bounds__(256) void k_ln_relu(const void* X,
    const float* __restrict__ g, const float* __restrict__ bta, unsigned short* Y){
  const int row = blockIdx.x, tid = threadIdx.x;
  const int d = tid * 4;
  float e0, e1, e2, e3;
  if (IN_BF16){
    us4 t = *(const us4*)((const unsigned short*)X + (size_t)row * 1024 + d);
    e0 = bf2f(t[0]); e1 = bf2f(t[1]); e2 = bf2f(t[2]); e3 = bf2f(t[3]);
  } else {
    float4 v = *(const float4*)((const float*)X + (size_t)row * 1024 + d);
    e0 = v.x; e1 = v.y; e2 = v.z; e3 = v.w;
  }
  float s1 = e0 + e1 + e2 + e3;
  float s2 = e0*e0 + e1*e1 + e2*e2 + e3*e3;
  #pragma unroll
  for (int m = 32; m >= 1; m >>= 1){ s1 += __shfl_xor(s1, m); s2 += __shfl_xor(s2, m); }
  __shared__ float a1[4], a2[4];
  int wave = tid >> 6, lane = tid & 63;
  if (lane == 0){ a1[wave] = s1; a2[wave] = s2; }
  __syncthreads();
  s1 = a1[0] + a1[1] + a1[2] + a1[3];
  s2 = a2[0] + a2[1] + a2[2] + a2[3];
  float mean = s1 * (1.f / 1024.f);
  float var  = s2 * (1.f / 1024.f) - mean * mean;
  float rstd = rsqrtf(var + 1e-5f);
  float4 gg = *(const float4*)(g + d);
  float4 bb = *(const float4*)(bta + d);
  us4 o;
  o[0] = f2bf(fmaxf((e0 - mean) * rstd * gg.x + bb.x, 0.f));
  o[1] = f2bf(fmaxf((e1 - mean) * rstd * gg.y + bb.y, 0.f));
  o[2] = f2bf(fmaxf((e2 - mean) * rstd * gg.z + bb.z, 0.f));
  o[3] = f2bf(fmaxf((e3 - mean) * rstd * gg.w + bb.w, 0.f));
  *(us4*)(Y + (size_t)row * 1024 + d) = o;
}

// ---------------- GRU cell elementwise: gi/gh packed in qgh [8192][6144] ----------------
__global__ __launch_bounds__(256) void k_gru(const unsigned short* __restrict__ qgh,
    const float* __restrict__ h, float* __restrict__ hn, unsigned short* __restrict__ hnbf){
  const int b = blockIdx.x;
  const int d = threadIdx.x * 4;
  const unsigned short* pi = qgh + (size_t)b * 6144;
  const unsigned short* ph = pi + 3072;
  us4 t;
  float ir[4], iz[4], in_[4], hr[4], hz[4], hnn[4];
  t = *(const us4*)(pi + d);        for (int j = 0; j < 4; ++j) ir[j]  = bf2f(t[j]);
  t = *(const us4*)(pi + 1024 + d); for (int j = 0; j < 4; ++j) iz[j]  = bf2f(t[j]);
  t = *(const us4*)(pi + 2048 + d); for (int j = 0; j < 4; ++j) in_[j] = bf2f(t[j]);
  t = *(const us4*)(ph + d);        for (int j = 0; j < 4; ++j) hr[j]  = bf2f(t[j]);
  t = *(const us4*)(ph + 1024 + d); for (int j = 0; j < 4; ++j) hz[j]  = bf2f(t[j]);
  t = *(const us4*)(ph + 2048 + d); for (int j = 0; j < 4; ++j) hnn[j] = bf2f(t[j]);
  float4 hv = *(const float4*)(h + (size_t)b * 1024 + d);
  float hvv[4] = {hv.x, hv.y, hv.z, hv.w};
  float ov[4]; us4 ob;
  #pragma unroll
  for (int j = 0; j < 4; ++j){
    float r = 1.f / (1.f + expf(-(ir[j] + hr[j])));
    float z = 1.f / (1.f + expf(-(iz[j] + hz[j])));
    float n = tanhf(in_[j] + r * hnn[j]);
    float o = (1.f - z) * n + z * hvv[j];
    ov[j] = o; ob[j] = f2bf(o);
  }
  float4 of; of.x = ov[0]; of.y = ov[1]; of.z = ov[2]; of.w = ov[3];
  *(float4*)(hn + (size_t)b * 1024 + d) = of;
  *(us4*)(hnbf + (size_t)b * 1024 + d) = ob;
}

// =========================== host ===========================
extern "C" void kernel_launch(void* const* d_in, const int* in_sizes, int n_in,
                              void* d_out, int out_size, void* d_ws, size_t ws_size,
                              hipStream_t stream) {
  (void)in_sizes; (void)n_in; (void)out_size;
  const float* query       = (const float*)d_in[0];
  const float* wm          = (const float*)d_in[1];
  const float* keys        = (const float*)d_in[2];
  const float* values      = (const float*)d_in[3];
  const float* last_access = (const float*)d_in[4];
  const float* importance  = (const float*)d_in[5];
  const float* consolid    = (const float*)d_in[6];
  const float* emo         = (const float*)d_in[7];
  const float* active      = (const float*)d_in[8];
  const float* in_proj_w   = (const float*)d_in[9];
  const float* in_proj_b   = (const float*)d_in[10];
  const float* out_w       = (const float*)d_in[11];
  const float* out_b       = (const float*)d_in[12];
  const float* msg_w1      = (const float*)d_in[13];
  const float* msg_b1      = (const float*)d_in[14];
  const float* msg_ln_g    = (const float*)d_in[15];
  const float* msg_ln_b    = (const float*)d_in[16];
  const float* msg_w2      = (const float*)d_in[17];
  const float* msg_b2      = (const float*)d_in[18];
  const float* gru_wih     = (const float*)d_in[19];
  const float* gru_whh     = (const float*)d_in[20];
  const float* gru_bih     = (const float*)d_in[21];
  const float* gru_bhh     = (const float*)d_in[22];
  const float* rsn_w1      = (const float*)d_in[23];
  const float* rsn_b1      = (const float*)d_in[24];
  const float* rsn_ln_g    = (const float*)d_in[25];
  const float* rsn_ln_b    = (const float*)d_in[26];
  const float* rsn_w2      = (const float*)d_in[27];
  const float* rsn_b2      = (const float*)d_in[28];
  float* out = (float*)d_out;

  // ---- workspace carve (lifetime-overlaid) ----
  size_t off = 0;
  char* base = (char*)d_ws;
  auto carve = [&](size_t bytes) -> char* {
    char* p = base + off;
    off += (bytes + 255) & ~(size_t)255;
    return p;
  };
  float* ascale = (float*)carve(4096*4);
  float* bbias  = (float*)carve(4096*4);
  float* qinv   = (float*)carve(8192*4);
  float* bc_pre = (float*)carve(1024*4);
  float* bc_gi  = (float*)carve(3072*4);
  float* bc_ih  = (float*)carve(6144*4);
  unsigned short* wb_ihh  = (unsigned short*)carve((size_t)6144*1024*2);  // 12 MiB [inproj;gwhh]
  unsigned short* wb_rw1  = (unsigned short*)carve((size_t)1024*1024*2);
  unsigned short* wb_rw2  = (unsigned short*)carve((size_t)1024*1024*2);
  unsigned short* wb_Wab  = (unsigned short*)carve((size_t)1024*2048*2);
  unsigned short* wb_Wc   = (unsigned short*)carve((size_t)3072*1024*2);
  unsigned short* schema_bf = (unsigned short*)carve((size_t)8192*1024*2); // 16 MiB (later: preln/h1)
  float*          state_f   = (float*)carve((size_t)8192*1024*4);
  unsigned short* state_bf  = (unsigned short*)carve((size_t)8192*1024*2);
  unsigned short* qkvM      = (unsigned short*)carve((size_t)8192*3072*2); // 48 MiB
  unsigned short* qgh       = (unsigned short*)carve((size_t)8192*6144*2); // 96 MiB [qkv|gh]

  if (off > ws_size){
    k_diag<<<1, 1, 0, stream>>>(out, (float)(ws_size >> 20));
    return;
  }

  // prep-phase temporaries (in qgh; dead before retrieval KX write? No — prep completes
  // before k_split3 writes KX into qgh start; stream-ordered)
  unsigned short* tmp_w1bf  = qgh + (size_t)8192*3072;            // second half of qgh
  unsigned short* tmp_outwT = tmp_w1bf + (size_t)1024*2048;
  unsigned short* tmp_w2T   = tmp_outwT + (size_t)1024*1024;
  unsigned short* tmp_wihbf = tmp_w2T + (size_t)1024*1024;

  // retrieval-phase overlays:
  unsigned short* QX = qkvM;                                  // 48 MiB [Qhi|Qlo|Qhi] K=3072
  unsigned short* KX = qgh;                                   // 24 MiB [Khi|Khi|Klo]
  float* candV = (float*)(qgh + (size_t)8192*3072);           // 8 MiB (disjoint from KX)
  int*   candI = (int*)((char*)candV + (size_t)8192*256*4);   // 8 MiB

  unsigned short* preln_h1 = schema_bf;   // reused per step (schema dead after qkvM GEMM)

  // ---- weight prep ----
  auto cast = [&](const float* src, unsigned short* dst, int n){
    k_cast_bf16<<<1024, 256, 0, stream>>>(src, dst, n / 4);
  };
  cast(in_proj_w, wb_ihh,                     3072*1024);
  cast(gru_whh,   wb_ihh + (size_t)3072*1024, 3072*1024);
  cast(rsn_w1,    wb_rw1,    1024*1024);
  cast(rsn_w2,    wb_rw2,    1024*1024);
  cast(msg_w1,    tmp_w1bf,  1024*2048);
  cast(gru_wih,   tmp_wihbf, 3072*1024);
  hipMemcpyAsync(bc_ih,        in_proj_b, 3072*4, hipMemcpyDeviceToDevice, stream);
  hipMemcpyAsync(bc_ih + 3072, gru_bhh,   3072*4, hipMemcpyDeviceToDevice, stream);
  k_tcast<<<dim3(32, 32), 256, 0, stream>>>(out_w,  tmp_outwT, 1024, 1024);
  k_tcast<<<dim3(32, 32), 256, 0, stream>>>(msg_w2, tmp_w2T,   1024, 1024);
  k_bias_pre<<<256, 256, 0, stream>>>(msg_w1, out_b, msg_b1, bc_pre);
  k_bias_gi<<<768, 256, 0, stream>>>(gru_wih, msg_b2, gru_bih, bc_gi);
  k_gemm<1><<<dim3(8, 8), 256, 0, stream>>>(tmp_w1bf,        tmp_outwT, nullptr, wb_Wab,        1024, 1024, 1024, 2048, 2048);
  k_gemm<1><<<dim3(8, 8), 256, 0, stream>>>(tmp_w1bf + 1024, tmp_outwT, nullptr, wb_Wab + 1024, 1024, 1024, 1024, 2048, 2048);
  k_gemm<1><<<dim3(24, 8), 256, 0, stream>>>(tmp_wihbf, tmp_w2T, nullptr, wb_Wc, 3072, 1024, 1024, 1024, 1024);

  // ---- retrieval ----
  k_qnorm<<<2048, 256, 0, stream>>>(query, qinv);
  k_prep_keys<<<1024, 256, 0, stream>>>(keys, last_access, importance, consolid, emo, active, ascale, bbias);
  k_split3<<<8192, 256, 0, stream>>>(query, qinv, QX, 0, 2048, 1024);   // [Qhi|Qlo|Qhi]
  k_split3<<<4096, 256, 0, stream>>>(keys, nullptr, KX, 0, 1024, 2048); // [Khi|Khi|Klo]
  k_scores8p<<<dim3(32, 16), 512, 0, stream>>>(QX, KX, ascale, bbias, candV, candI);
  k_topk_merge<<<8192, 256, 0, stream>>>(candV, candI, values, schema_bf);

  // ---- reasoner ----
  k_initstate<<<8192, 256, 0, stream>>>(wm, state_f, state_bf);
  // schema token qkv (loop-invariant) — uses first 3072 rows of wb_ihh (= inproj)
  k_gemm8p<1><<<dim3(32, 12), 512, 0, stream>>>(schema_bf, wb_ihh, bc_ih, qkvM, 8192, 3072, 1024, 1024, 3072);
  for (int s = 0; s < 3; ++s){
    // merged: [qkv | gh] = state @ [inproj ; gwhh]^T  — 768 blocks = exactly 3 CU-waves
    k_gemm8p<1><<<dim3(32, 24), 512, 0, stream>>>(state_bf, wb_ihh, bc_ih, qgh, 8192, 6144, 1024, 1024, 6144);
    k_attn<<<8192, 256, 0, stream>>>(qgh, qkvM);
    // preln(bf16) = catt(qgh cols 0..2047) @ [Wa|Wb]^T + bc_pre  -> schema region
    k_gemm<1><<<dim3(64, 8), 256, 0, stream>>>(qgh, wb_Wab, bc_pre, preln_h1, 8192, 1024, 2048, 6144, 1024);
    k_ln_relu<1><<<8192, 256, 0, stream>>>(preln_h1, msg_ln_g, msg_ln_b, preln_h1); // in-place
    // gi = h1 @ Wc^T + bc_gi  -> qgh cols 0..3071 (qkv region dead after preln GEMM)
    k_gemm8p<1><<<dim3(32, 12), 512, 0, stream>>>(preln_h1, wb_Wc, bc_gi, qgh, 8192, 3072, 1024, 1024, 6144);
    k_gru<<<8192, 256, 0, stream>>>(qgh, state_f, state_f, state_bf);
  }
  // ---- head (qgh fully dead) ----
  float* hpre = (float*)qgh;                                   // 32 MiB
  unsigned short* hh1 = qgh + (size_t)8192*3072;               // 16 MiB, disjoint
  k_gemm<0><<<dim3(64, 8), 256, 0, stream>>>(state_bf, wb_rw1, rsn_b1, hpre, 8192, 1024, 1024, 1024, 1024);
  k_ln_relu<0><<<8192, 256, 0, stream>>>(hpre, rsn_ln_g, rsn_ln_b, hh1);
  k_gemm<0><<<dim3(64, 8), 256, 0, stream>>>(hh1, wb_rw2, rsn_b2, out, 8192, 1024, 1024, 1024, 1024);
}

// Round 13
// 1490.641 us; speedup vs baseline: 1.0106x; 1.0106x over previous
//
#include <hip/hip_runtime.h>
#include <cstdint>
#include <cstddef>

typedef __attribute__((ext_vector_type(8))) short short8;
typedef __attribute__((ext_vector_type(4))) float f32x4;
typedef __attribute__((ext_vector_type(4))) unsigned short us4;

#define DEVINL static __device__ __forceinline__
#define AS1 __attribute__((address_space(1)))
#define AS3 __attribute__((address_space(3)))

DEVINL float bf2f(unsigned short u){
  union { unsigned uu; float f; } v; v.uu = ((unsigned)u) << 16; return v.f;
}
DEVINL unsigned short f2bf(float f){
  unsigned u = __float_as_uint(f);
  u += 0x7fffu + ((u >> 16) & 1u);
  return (unsigned short)(u >> 16);
}

// strict total order: value desc, index asc (JAX top_k tie semantics)
DEVINL bool tk_better(float av, int ai, float bv, int bi){
  return (av > bv) || (av == bv && ai < bi);
}
DEVINL void tk_cmpex(float& va, int& ia, float& vb, int& ib){
  if (!tk_better(va, ia, vb, ib)){
    float tv = va; va = vb; vb = tv;
    int t = ia; ia = ib; ib = t;
  }
}
DEVINL void tk_sort4(float* v, int* id){
  tk_cmpex(v[0], id[0], v[1], id[1]);
  tk_cmpex(v[2], id[2], v[3], id[3]);
  tk_cmpex(v[0], id[0], v[2], id[2]);
  tk_cmpex(v[1], id[1], v[3], id[3]);
  tk_cmpex(v[1], id[1], v[2], id[2]);
}
DEVINL void tk_bmerge(float* v, int* id, const float* pv, const int* pi){
  #pragma unroll
  for (int i = 0; i < 4; ++i){
    bool ta = tk_better(v[i], id[i], pv[3 - i], pi[3 - i]);
    v[i]  = ta ? v[i]  : pv[3 - i];
    id[i] = ta ? id[i] : pi[3 - i];
  }
  tk_cmpex(v[0], id[0], v[2], id[2]);
  tk_cmpex(v[1], id[1], v[3], id[3]);
  tk_cmpex(v[0], id[0], v[1], id[1]);
  tk_cmpex(v[2], id[2], v[3], id[3]);
}

__global__ void k_diag(float* out, float v){ out[0] = v; }

// ---------------- cast f32 -> bf16 ----------------
__global__ __launch_bounds__(256) void k_cast_bf16(const float* __restrict__ x,
                                                   unsigned short* __restrict__ y, int n4){
  int stride = gridDim.x * blockDim.x;
  for (int i = blockIdx.x * blockDim.x + threadIdx.x; i < n4; i += stride){
    float4 v = ((const float4*)x)[i];
    us4 o; o[0] = f2bf(v.x); o[1] = f2bf(v.y); o[2] = f2bf(v.z); o[3] = f2bf(v.w);
    ((us4*)y)[i] = o;
  }
}

// ---------------- transpose-cast f32 [R][C] -> bf16 [C][R] ----------------
__global__ __launch_bounds__(256) void k_tcast(const float* __restrict__ in,
    unsigned short* __restrict__ outT, int R, int C){
  __shared__ float t[32][33];
  const int bc = blockIdx.x * 32, br = blockIdx.y * 32;
  const int lx = threadIdx.x & 31, ly = threadIdx.x >> 5;
  #pragma unroll
  for (int i = 0; i < 32; i += 8)
    t[ly + i][lx] = in[(size_t)(br + ly + i) * C + bc + lx];
  __syncthreads();
  #pragma unroll
  for (int i = 0; i < 32; i += 8)
    outT[(size_t)(bc + ly + i) * R + br + lx] = f2bf(t[lx][ly + i]);
}

// ---------------- bias precompute: bc[j] = sum_m w1[j,m]*outb[m&1023] + b1[j] ----------------
__global__ __launch_bounds__(256) void k_bias_pre(const float* __restrict__ w1,
    const float* __restrict__ outb, const float* __restrict__ b1, float* __restrict__ bc){
  int wave = threadIdx.x >> 6, lane = threadIdx.x & 63;
  int j = blockIdx.x * 4 + wave;
  float s = 0.f;
  for (int m = lane; m < 2048; m += 64)
    s += w1[(size_t)j * 2048 + m] * outb[m & 1023];
  #pragma unroll
  for (int m = 32; m >= 1; m >>= 1) s += __shfl_xor(s, m);
  if (lane == 0) bc[j] = s + b1[j];
}

// ---------------- bias precompute: bc[n] = sum_m wih[n,m]*b2[m] + bih[n] ----------------
__global__ __launch_bounds__(256) void k_bias_gi(const float* __restrict__ wih,
    const float* __restrict__ b2, const float* __restrict__ bih, float* __restrict__ bc){
  int wave = threadIdx.x >> 6, lane = threadIdx.x & 63;
  int n = blockIdx.x * 4 + wave;
  float s = 0.f;
  for (int m = lane; m < 1024; m += 64)
    s += wih[(size_t)n * 1024 + m] * b2[m];
  #pragma unroll
  for (int m = 32; m >= 1; m >>= 1) s += __shfl_xor(s, m);
  if (lane == 0) bc[n] = s + bih[n];
}

// ---------------- fused Q: row norm + split f32 -> (hi, lo) bf16, scaled by 1/|q| ----------------
__global__ __launch_bounds__(256) void k_splitq(const float* __restrict__ X,
    unsigned short* __restrict__ Hi, unsigned short* __restrict__ Lo){
  const int row = blockIdx.x, tid = threadIdx.x;
  const int d = tid * 4;
  float4 v = *(const float4*)(X + (size_t)row * 1024 + d);
  float ss = v.x*v.x + v.y*v.y + v.z*v.z + v.w*v.w;
  #pragma unroll
  for (int m = 32; m >= 1; m >>= 1) ss += __shfl_xor(ss, m);
  __shared__ float a[4];
  int wave = tid >> 6, lane = tid & 63;
  if (lane == 0) a[wave] = ss;
  __syncthreads();
  float s = a[0] + a[1] + a[2] + a[3];
  float sc = 1.0f / fmaxf(sqrtf(s), 1e-8f);
  float xs[4] = {v.x * sc, v.y * sc, v.z * sc, v.w * sc};
  us4 h, l;
  #pragma unroll
  for (int j = 0; j < 4; ++j){
    unsigned short hb = f2bf(xs[j]);
    h[j] = hb;
    l[j] = f2bf(xs[j] - bf2f(hb));
  }
  *(us4*)(Hi + (size_t)row * 1024 + d) = h;
  *(us4*)(Lo + (size_t)row * 1024 + d) = l;
}

// ---------------- fused K: row norm + ascale/bbias + split (unscaled) ----------------
__global__ __launch_bounds__(256) void k_splitk(const float* __restrict__ keys,
    const float* __restrict__ last_access, const float* __restrict__ importance,
    const float* __restrict__ consolid, const float* __restrict__ emo,
    const float* __restrict__ active, float* __restrict__ ascale, float* __restrict__ bbias,
    unsigned short* __restrict__ Hi, unsigned short* __restrict__ Lo){
  const int row = blockIdx.x, tid = threadIdx.x;
  const int d = tid * 4;
  float4 v = *(const float4*)(keys + (size_t)row * 1024 + d);
  float ss = v.x*v.x + v.y*v.y + v.z*v.z + v.w*v.w;
  #pragma unroll
  for (int m = 32; m >= 1; m >>= 1) ss += __shfl_xor(ss, m);
  __shared__ float a[4];
  int wave = tid >> 6, lane = tid & 63;
  if (lane == 0) a[wave] = ss;
  __syncthreads();
  float s = a[0] + a[1] + a[2] + a[3];
  if (tid == 0){
    float norm = fmaxf(sqrtf(s), 1e-8f);
    float forget = expf(-0.001f * (100.0f - last_access[row]));
    float bo = 0.f;
    #pragma unroll
    for (int j = 0; j < 8; ++j) bo += emo[row * 8 + j];
    bo = bo * 0.1f + importance[row] * 0.2f + log1pf(consolid[row]) * 0.1f;
    float act = active[row];
    ascale[row] = forget * act / norm;
    bbias[row]  = bo * act;
  }
  us4 h, l;
  float xs[4] = {v.x, v.y, v.z, v.w};
  #pragma unroll
  for (int j = 0; j < 4; ++j){
    unsigned short hb = f2bf(xs[j]);
    h[j] = hb;
    l[j] = f2bf(xs[j] - bf2f(hb));
  }
  *(us4*)(Hi + (size_t)row * 1024 + d) = h;
  *(us4*)(Lo + (size_t)row * 1024 + d) = l;
}

// ---------------- split-bf16 MFMA scores GEMM + fused per-subtile top-4 (R11/R9 version) ----------
__global__ __launch_bounds__(256) void k_scores_mfma(
    const unsigned short* __restrict__ Qhi, const unsigned short* __restrict__ Qlo,
    const unsigned short* __restrict__ Khi, const unsigned short* __restrict__ Klo,
    const float* __restrict__ ascale, const float* __restrict__ bbias,
    float* __restrict__ candV, int* __restrict__ candI){
  __shared__ __align__(16) unsigned short AsH[128 * 32];
  __shared__ __align__(16) unsigned short AsL[128 * 32];
  __shared__ __align__(16) unsigned short BsH[128 * 32];
  __shared__ __align__(16) unsigned short BsL[128 * 32];
  const int tid = threadIdx.x;
  const int wave = tid >> 6, lane = tid & 63;
  const int tM = blockIdx.x, tN = blockIdx.y;
  const int wm_ = wave >> 1, wn_ = wave & 1;
  f32x4 acc[4][4] = {};
  const unsigned short* AH = Qhi + (size_t)tM * 128 * 1024;
  const unsigned short* AL = Qlo + (size_t)tM * 128 * 1024;
  const unsigned short* BH = Khi + (size_t)tN * 128 * 1024;
  const unsigned short* BL = Klo + (size_t)tN * 128 * 1024;
  const int lrow = lane & 15, lk = (lane >> 4) * 8;
  for (int k0 = 0; k0 < 1024; k0 += 32){
    __syncthreads();
    #pragma unroll
    for (int j = 0; j < 2; ++j){
      int c = wave * 128 + j * 64 + lane;
      int row = c >> 2, cp = c & 3;
      size_t go = (size_t)row * 1024 + k0 + cp * 8;
      int lo_ = (wave * 2 + j) * 512;
      __builtin_amdgcn_global_load_lds((const AS1 void*)(AH + go), (AS3 void*)(AsH + lo_), 16, 0, 0);
      __builtin_amdgcn_global_load_lds((const AS1 void*)(AL + go), (AS3 void*)(AsL + lo_), 16, 0, 0);
      __builtin_amdgcn_global_load_lds((const AS1 void*)(BH + go), (AS3 void*)(BsH + lo_), 16, 0, 0);
      __builtin_amdgcn_global_load_lds((const AS1 void*)(BL + go), (AS3 void*)(BsL + lo_), 16, 0, 0);
    }
    __syncthreads();
    short8 ah[4], al[4], bh[4], bl[4];
    #pragma unroll
    for (int mi = 0; mi < 4; ++mi){
      int ro = (wm_ * 64 + mi * 16 + lrow) * 32 + lk;
      ah[mi] = *(const short8*)(AsH + ro);
      al[mi] = *(const short8*)(AsL + ro);
    }
    #pragma unroll
    for (int ni = 0; ni < 4; ++ni){
      int ro = (wn_ * 64 + ni * 16 + lrow) * 32 + lk;
      bh[ni] = *(const short8*)(BsH + ro);
      bl[ni] = *(const short8*)(BsL + ro);
    }
    #pragma unroll
    for (int mi = 0; mi < 4; ++mi)
      #pragma unroll
      for (int ni = 0; ni < 4; ++ni){
        acc[mi][ni] = __builtin_amdgcn_mfma_f32_16x16x32_bf16(ah[mi], bh[ni], acc[mi][ni], 0, 0, 0);
        acc[mi][ni] = __builtin_amdgcn_mfma_f32_16x16x32_bf16(ah[mi], bl[ni], acc[mi][ni], 0, 0, 0);
        acc[mi][ni] = __builtin_amdgcn_mfma_f32_16x16x32_bf16(al[mi], bh[ni], acc[mi][ni], 0, 0, 0);
      }
  }
  const int lc = lane & 15;
  float as_[4], bb_[4]; int cid[4];
  #pragma unroll
  for (int ni = 0; ni < 4; ++ni){
    cid[ni] = tN * 128 + wn_ * 64 + ni * 16 + lc;
    as_[ni] = ascale[cid[ni]];
    bb_[ni] = bbias[cid[ni]];
  }
  #pragma unroll
  for (int mi = 0; mi < 4; ++mi){
    #pragma unroll
    for (int r = 0; r < 4; ++r){
      float v[4]; int id[4];
      #pragma unroll
      for (int ni = 0; ni < 4; ++ni){
        v[ni]  = acc[mi][ni][r] * as_[ni] + bb_[ni];
        id[ni] = cid[ni];
      }
      tk_sort4(v, id);
      #pragma unroll
      for (int mask = 1; mask <= 8; mask <<= 1){
        float pv[4]; int pi_[4];
        #pragma unroll
        for (int j = 0; j < 4; ++j){
          pv[j]  = __shfl_xor(v[j], mask);
          pi_[j] = __shfl_xor(id[j], mask);
        }
        tk_bmerge(v, id, pv, pi_);
      }
      if (lc == 0){
        int row = tM * 128 + wm_ * 64 + mi * 16 + (lane >> 4) * 4 + r;
        size_t cb = (size_t)row * 256 + tN * 8 + wn_ * 4;
        #pragma unroll
        for (int j = 0; j < 4; ++j){ candV[cb + j] = v[j]; candI[cb + j] = id[j]; }
      }
    }
  }
}

// ---------------- merge 256 candidates/row -> top-4 + softmax + V gather ----------------
__global__ __launch_bounds__(256) void k_topk_merge(const float* __restrict__ candV,
    const int* __restrict__ candI, const float* __restrict__ V,
    unsigned short* __restrict__ schema_bf){
  const int row = blockIdx.x, tid = threadIdx.x;
  const int wave = tid >> 6, lane = tid & 63;
  float v[4]; int id[4];
  v[0] = candV[(size_t)row * 256 + tid];
  id[0] = candI[(size_t)row * 256 + tid];
  #pragma unroll
  for (int j = 1; j < 4; ++j){ v[j] = -3.4e38f; id[j] = 0x7fffffff; }
  #pragma unroll
  for (int mask = 1; mask <= 32; mask <<= 1){
    float pv[4]; int pi_[4];
    #pragma unroll
    for (int j = 0; j < 4; ++j){
      pv[j]  = __shfl_xor(v[j], mask);
      pi_[j] = __shfl_xor(id[j], mask);
    }
    tk_bmerge(v, id, pv, pi_);
  }
  __shared__ float wv[4][4]; __shared__ int wi[4][4];
  if (lane == 0){
    #pragma unroll
    for (int j = 0; j < 4; ++j){ wv[wave][j] = v[j]; wi[wave][j] = id[j]; }
  }
  __syncthreads();
  __shared__ float w_sh[4]; __shared__ int i_sh[4];
  if (tid == 0){
    float fv[4]; int fi[4];
    #pragma unroll
    for (int j = 0; j < 4; ++j){ fv[j] = wv[0][j]; fi[j] = wi[0][j]; }
    #pragma unroll
    for (int w = 1; w < 4; ++w){
      float pv[4]; int pi_[4];
      #pragma unroll
      for (int j = 0; j < 4; ++j){ pv[j] = wv[w][j]; pi_[j] = wi[w][j]; }
      tk_bmerge(fv, fi, pv, pi_);
    }
    float m = fv[0];
    float e0 = expf(fv[0] - m), e1 = expf(fv[1] - m), e2 = expf(fv[2] - m), e3 = expf(fv[3] - m);
    float inv = 1.f / (e0 + e1 + e2 + e3);
    w_sh[0] = e0 * inv; w_sh[1] = e1 * inv; w_sh[2] = e2 * inv; w_sh[3] = e3 * inv;
    i_sh[0] = fi[0]; i_sh[1] = fi[1]; i_sh[2] = fi[2]; i_sh[3] = fi[3];
  }
  __syncthreads();
  float w0 = w_sh[0], w1 = w_sh[1], w2 = w_sh[2], w3 = w_sh[3];
  const float* v0 = V + (size_t)i_sh[0] * 1024;
  const float* v1 = V + (size_t)i_sh[1] * 1024;
  const float* v2 = V + (size_t)i_sh[2] * 1024;
  const float* v3 = V + (size_t)i_sh[3] * 1024;
  int d = tid * 4;
  float4 a = *(const float4*)(v0 + d);
  float4 b4 = *(const float4*)(v1 + d);
  float4 c = *(const float4*)(v2 + d);
  float4 e = *(const float4*)(v3 + d);
  us4 o;
  o[0] = f2bf(w0*a.x + w1*b4.x + w2*c.x + w3*e.x);
  o[1] = f2bf(w0*a.y + w1*b4.y + w2*c.y + w3*e.y);
  o[2] = f2bf(w0*a.z + w1*b4.z + w2*c.z + w3*e.z);
  o[3] = f2bf(w0*a.w + w1*b4.w + w2*c.w + w3*e.w);
  *(us4*)(schema_bf + (size_t)row * 1024 + d) = o;
}

// ---------------- state init ----------------
__global__ __launch_bounds__(256) void k_initstate(const float* __restrict__ wm,
    float* __restrict__ st, unsigned short* __restrict__ stbf){
  size_t i = ((size_t)blockIdx.x * 256 + threadIdx.x) * 4;
  float4 v = *(const float4*)(wm + i);
  *(float4*)(st + i) = v;
  us4 o; o[0] = f2bf(v.x); o[1] = f2bf(v.y); o[2] = f2bf(v.z); o[3] = f2bf(v.w);
  *(us4*)(stbf + i) = o;
}

// ---------------- 128x128 bf16 MFMA GEMM ----------------
template<int OUT_BF16>
__global__ __launch_bounds__(256) void k_gemm(const unsigned short* __restrict__ A,
    const unsigned short* __restrict__ W, const float* __restrict__ bias,
    void* __restrict__ C, int M, int N, int K, int lda, int ldc){
  __shared__ __align__(16) unsigned short As[128 * 32];
  __shared__ __align__(16) unsigned short Ws[128 * 32];
  const int tid = threadIdx.x;
  const int wave = tid >> 6, lane = tid & 63;
  const int tM = blockIdx.x, tN = blockIdx.y;
  const int wm_ = wave >> 1, wn_ = wave & 1;
  f32x4 acc[4][4] = {};
  const unsigned short* Abase = A + (size_t)tM * 128 * lda;
  const unsigned short* Wbase = W + (size_t)tN * 128 * K;
  const int lrow = lane & 15, lk = (lane >> 4) * 8;
  for (int k0 = 0; k0 < K; k0 += 32){
    __syncthreads();
    #pragma unroll
    for (int j = 0; j < 2; ++j){
      int c = wave * 128 + j * 64 + lane;
      int row = c >> 2, cp = c & 3;
      const unsigned short* ga = Abase + (size_t)row * lda + k0 + cp * 8;
      const unsigned short* gw = Wbase + (size_t)row * K + k0 + cp * 8;
      __builtin_amdgcn_global_load_lds((const AS1 void*)ga, (AS3 void*)(As + (wave * 2 + j) * 512), 16, 0, 0);
      __builtin_amdgcn_global_load_lds((const AS1 void*)gw, (AS3 void*)(Ws + (wave * 2 + j) * 512), 16, 0, 0);
    }
    __syncthreads();
    short8 af[4], bfr[4];
    #pragma unroll
    for (int mi = 0; mi < 4; ++mi)
      af[mi] = *(const short8*)(As + (wm_ * 64 + mi * 16 + lrow) * 32 + lk);
    #pragma unroll
    for (int ni = 0; ni < 4; ++ni)
      bfr[ni] = *(const short8*)(Ws + (wn_ * 64 + ni * 16 + lrow) * 32 + lk);
    #pragma unroll
    for (int mi = 0; mi < 4; ++mi)
      #pragma unroll
      for (int ni = 0; ni < 4; ++ni)
        acc[mi][ni] = __builtin_amdgcn_mfma_f32_16x16x32_bf16(af[mi], bfr[ni], acc[mi][ni], 0, 0, 0);
  }
  const int lc = lane & 15, lr = (lane >> 4) * 4;
  #pragma unroll
  for (int ni = 0; ni < 4; ++ni){
    int col = tN * 128 + wn_ * 64 + ni * 16 + lc;
    float bb = bias ? bias[col] : 0.f;
    #pragma unroll
    for (int mi = 0; mi < 4; ++mi){
      int rowb = tM * 128 + wm_ * 64 + mi * 16 + lr;
      #pragma unroll
      for (int r = 0; r < 4; ++r){
        float vv = acc[mi][ni][r] + bb;
        size_t off = (size_t)(rowb + r) * ldc + col;
        if (OUT_BF16) ((unsigned short*)C)[off] = f2bf(vv);
        else ((float*)C)[off] = vv;
      }
    }
  }
}

// ---------------- 256x256 8-phase bf16 MFMA GEMM (R9 verified schedule) ----------------
template<int OUT_BF16>
__global__ __launch_bounds__(512, 2) void k_gemm8p(const unsigned short* __restrict__ A,
    const unsigned short* __restrict__ W, const float* __restrict__ bias,
    void* __restrict__ C, int M, int N, int K, int lda, int ldc){
  __shared__ __align__(16) unsigned short lds[65536];
  const int tid = threadIdx.x;
  const int wave = tid >> 6, lane = tid & 63;
  const int wqr = wave >> 2, wqc = wave & 3;
  const int lrow = lane & 15, lkk = lane >> 4;

  const int nwg = gridDim.x * gridDim.y;
  int lin = blockIdx.y * gridDim.x + blockIdx.x;
  int cpx = nwg >> 3;
  int swz = (lin & 7) * cpx + (lin >> 3);
  const int nM = M >> 8;
  const int tM = swz % nM, tN = swz / nM;

  const unsigned short* Abase = A + (size_t)tM * 256 * lda;
  const unsigned short* Wbase = W + (size_t)tN * 256 * K;

  f32x4 a00[4][2] = {}, a01[4][2] = {}, a11[4][2] = {}, a10[4][2] = {};
  short8 af[4][2], bf[2][2];
  const int ntiles = K >> 6;

  auto stage = [&](int op, int slot, int half, int tile){
    if (tile >= ntiles) return;
    const unsigned short* G = op ? Wbase : Abase;
    const int rs = op ? K : lda;
    const int k0 = tile * 64, hr = half * 128;
    const int base = op * 32768 + slot * 16384 + half * 8192;
    #pragma unroll
    for (int l = 0; l < 2; ++l){
      int p = l * 512 + tid;
      int row = p >> 3, c = (p & 7) ^ (row & 7);
      int dstc = l * 512 + wave * 64;
      __builtin_amdgcn_global_load_lds(
          (const AS1 void*)(G + (size_t)(hr + row) * rs + k0 + c * 8),
          (AS3 void*)(lds + base + dstc * 8), 16, 0, 0);
    }
  };
  auto ldA = [&](int slot, int half){
    const int base = slot * 16384 + half * 8192;
    #pragma unroll
    for (int mi = 0; mi < 4; ++mi)
      #pragma unroll
      for (int kk = 0; kk < 2; ++kk){
        int row = wqr * 64 + mi * 16 + lrow;
        int c = kk * 4 + lkk;
        af[mi][kk] = *(const short8*)(lds + base + (row * 8 + (c ^ (row & 7))) * 8);
      }
  };
  auto ldB = [&](int slot, int half){
    const int base = 32768 + slot * 16384 + half * 8192;
    #pragma unroll
    for (int ni = 0; ni < 2; ++ni)
      #pragma unroll
      for (int kk = 0; kk < 2; ++kk){
        int row = wqc * 32 + ni * 16 + lrow;
        int c = kk * 4 + lkk;
        bf[ni][kk] = *(const short8*)(lds + base + (row * 8 + (c ^ (row & 7))) * 8);
      }
  };
  auto mfma16 = [&](f32x4 (&acc)[4][2]){
    __builtin_amdgcn_s_setprio(1);
    #pragma unroll
    for (int mi = 0; mi < 4; ++mi)
      #pragma unroll
      for (int ni = 0; ni < 2; ++ni)
        #pragma unroll
        for (int kk = 0; kk < 2; ++kk)
          acc[mi][ni] = __builtin_amdgcn_mfma_f32_16x16x32_bf16(af[mi][kk], bf[ni][kk], acc[mi][ni], 0, 0, 0);
    __builtin_amdgcn_s_setprio(0);
  };
  auto SB = [&](){
    __builtin_amdgcn_sched_barrier(0);
    __builtin_amdgcn_s_barrier();
    __builtin_amdgcn_sched_barrier(0);
  };

  stage(0,0,0, 0); stage(1,0,0, 0); stage(1,0,1, 0); stage(0,0,1, 0);
  stage(0,1,0, 1); stage(1,1,1, 1);
  __builtin_amdgcn_sched_barrier(0);
  asm volatile("s_waitcnt vmcnt(4)" ::: "memory");
  __builtin_amdgcn_s_barrier();
  __builtin_amdgcn_sched_barrier(0);

  for (int j = 0; j < (ntiles >> 1); ++j){
    const int t0 = 2 * j;
    ldA(0,0); ldB(0,0); stage(0,1,1, t0+1);
    SB(); mfma16(a00); SB();
    ldB(0,1); stage(1,1,0, t0+1);
    SB(); mfma16(a01); SB();
    ldA(0,1); stage(0,0,0, t0+2);
    SB(); mfma16(a11); SB();
    ldB(0,0); stage(1,0,1, t0+2);
    SB(); mfma16(a10);
    __builtin_amdgcn_sched_barrier(0);
    if (t0 + 2 < ntiles) asm volatile("s_waitcnt vmcnt(4)" ::: "memory");
    else                 asm volatile("s_waitcnt vmcnt(0)" ::: "memory");
    __builtin_amdgcn_s_barrier();
    __builtin_amdgcn_sched_barrier(0);
    ldA(1,0); ldB(1,0); stage(0,0,1, t0+2);
    SB(); mfma16(a00); SB();
    ldB(1,1); stage(1,0,0, t0+2);
    SB(); mfma16(a01); SB();
    ldA(1,1); stage(0,1,0, t0+3);
    SB(); mfma16(a11); SB();
    ldB(1,0); stage(1,1,1, t0+3);
    SB(); mfma16(a10);
    __builtin_amdgcn_sched_barrier(0);
    asm volatile("s_waitcnt vmcnt(4)" ::: "memory");
    __builtin_amdgcn_s_barrier();
    __builtin_amdgcn_sched_barrier(0);
  }

  const int lc = lane & 15, lr = (lane >> 4) * 4;
  auto wout = [&](f32x4 (&acc)[4][2], int MH, int NH){
    #pragma unroll
    for (int ni = 0; ni < 2; ++ni){
      int col = tN * 256 + NH * 128 + wqc * 32 + ni * 16 + lc;
      float bb = bias ? bias[col] : 0.f;
      #pragma unroll
      for (int mi = 0; mi < 4; ++mi){
        int rowb = tM * 256 + MH * 128 + wqr * 64 + mi * 16 + lr;
        #pragma unroll
        for (int r = 0; r < 4; ++r){
          float vv = acc[mi][ni][r] + bb;
          size_t off = (size_t)(rowb + r) * ldc + col;
          if (OUT_BF16) ((unsigned short*)C)[off] = f2bf(vv);
          else ((float*)C)[off] = vv;
        }
      }
    }
  };
  wout(a00, 0, 0); wout(a01, 0, 1); wout(a11, 1, 1); wout(a10, 1, 0);
}

// ---------------- 2-token MHA, in-place into qgh cols 0..2047 ----------------
__global__ __launch_bounds__(256) void k_attn(unsigned short* qgh,
    const unsigned short* __restrict__ qkvM){
  const int b = blockIdx.x, tid = threadIdx.x;
  const int l = tid & 31;
  const int e = (tid >> 5) * 128 + l * 4;
  unsigned short* ps = qgh + (size_t)b * 6144;
  const unsigned short* pm = qkvM + (size_t)b * 3072;
  float q0[4], kk0[4], v0[4], q1[4], kk1[4], v1[4];
  us4 t;
  t = *(const us4*)(ps + e);        for (int j = 0; j < 4; ++j) q0[j]  = bf2f(t[j]);
  t = *(const us4*)(ps + 1024 + e); for (int j = 0; j < 4; ++j) kk0[j] = bf2f(t[j]);
  t = *(const us4*)(ps + 2048 + e); for (int j = 0; j < 4; ++j) v0[j]  = bf2f(t[j]);
  t = *(const us4*)(pm + e);        for (int j = 0; j < 4; ++j) q1[j]  = bf2f(t[j]);
  t = *(const us4*)(pm + 1024 + e); for (int j = 0; j < 4; ++j) kk1[j] = bf2f(t[j]);
  t = *(const us4*)(pm + 2048 + e); for (int j = 0; j < 4; ++j) v1[j]  = bf2f(t[j]);
  float s00 = 0.f, s01 = 0.f, s10 = 0.f, s11 = 0.f;
  #pragma unroll
  for (int j = 0; j < 4; ++j){
    s00 += q0[j] * kk0[j]; s01 += q0[j] * kk1[j];
    s10 += q1[j] * kk0[j]; s11 += q1[j] * kk1[j];
  }
  #pragma unroll
  for (int m = 16; m >= 1; m >>= 1){
    s00 += __shfl_xor(s00, m); s01 += __shfl_xor(s01, m);
    s10 += __shfl_xor(s10, m); s11 += __shfl_xor(s11, m);
  }
  const float sc = 0.08838834764831845f; // 1/sqrt(128)
  s00 *= sc; s01 *= sc; s10 *= sc; s11 *= sc;
  float m0 = fmaxf(s00, s01), m1 = fmaxf(s10, s11);
  float e00 = expf(s00 - m0), e01 = expf(s01 - m0);
  float e10 = expf(s10 - m1), e11 = expf(s11 - m1);
  float i0 = 1.f / (e00 + e01), i1 = 1.f / (e10 + e11);
  float w00 = e00 * i0, w01 = e01 * i0, w10 = e10 * i1, w11 = e11 * i1;
  us4 o0, o1;
  #pragma unroll
  for (int j = 0; j < 4; ++j){
    o0[j] = f2bf(w00 * v0[j] + w01 * v1[j]);
    o1[j] = f2bf(w10 * v0[j] + w11 * v1[j]);
  }
  *(us4*)(ps + e)        = o0;
  *(us4*)(ps + 1024 + e) = o1;
}

// ---------------- row LayerNorm + ReLU -> bf16 (f32 or bf16 input) ----------------
template<int IN_BF16>
__global__ __launch_bounds__(256) void k_ln_relu(const void* X,
    const float* __restrict__ g, const float* __restrict__ bta, unsigned short* Y){
  const int row = blockIdx.x, tid = threadIdx.x;
  const int d = tid * 4;
  float e0, e1, e2, e3;
  if (IN_BF16){
    us4 t = *(const us4*)((const unsigned short*)X + (size_t)row * 1024 + d);
    e0 = bf2f(t[0]); e1 = bf2f(t[1]); e2 = bf2f(t[2]); e3 = bf2f(t[3]);
  } else {
    float4 v = *(const float4*)((const float*)X + (size_t)row * 1024 + d);
    e0 = v.x; e1 = v.y; e2 = v.z; e3 = v.w;
  }
  float s1 = e0 + e1 + e2 + e3;
  float s2 = e0*e0 + e1*e1 + e2*e2 + e3*e3;
  #pragma unroll
  for (int m = 32; m >= 1; m >>= 1){ s1 += __shfl_xor(s1, m); s2 += __shfl_xor(s2, m); }
  __shared__ float a1[4], a2[4];
  int wave = tid >> 6, lane = tid & 63;
  if (lane == 0){ a1[wave] = s1; a2[wave] = s2; }
  __syncthreads();
  s1 = a1[0] + a1[1] + a1[2] + a1[3];
  s2 = a2[0] + a2[1] + a2[2] + a2[3];
  float mean = s1 * (1.f / 1024.f);
  float var  = s2 * (1.f / 1024.f) - mean * mean;
  float rstd = rsqrtf(var + 1e-5f);
  float4 gg = *(const float4*)(g + d);
  float4 bb = *(const float4*)(bta + d);
  us4 o;
  o[0] = f2bf(fmaxf((e0 - mean) * rstd * gg.x + bb.x, 0.f));
  o[1] = f2bf(fmaxf((e1 - mean) * rstd * gg.y + bb.y, 0.f));
  o[2] = f2bf(fmaxf((e2 - mean) * rstd * gg.z + bb.z, 0.f));
  o[3] = f2bf(fmaxf((e3 - mean) * rstd * gg.w + bb.w, 0.f));
  *(us4*)(Y + (size_t)row * 1024 + d) = o;
}

// ---------------- GRU cell elementwise: gi/gh packed in qgh [8192][6144] ----------------
__global__ __launch_bounds__(256) void k_gru(const unsigned short* __restrict__ qgh,
    const float* __restrict__ h, float* __restrict__ hn, unsigned short* __restrict__ hnbf){
  const int b = blockIdx.x;
  const int d = threadIdx.x * 4;
  const unsigned short* pi = qgh + (size_t)b * 6144;
  const unsigned short* ph = pi + 3072;
  us4 t;
  float ir[4], iz[4], in_[4], hr[4], hz[4], hnn[4];
  t = *(const us4*)(pi + d);        for (int j = 0; j < 4; ++j) ir[j]  = bf2f(t[j]);
  t = *(const us4*)(pi + 1024 + d); for (int j = 0; j < 4; ++j) iz[j]  = bf2f(t[j]);
  t = *(const us4*)(pi + 2048 + d); for (int j = 0; j < 4; ++j) in_[j] = bf2f(t[j]);
  t = *(const us4*)(ph + d);        for (int j = 0; j < 4; ++j) hr[j]  = bf2f(t[j]);
  t = *(const us4*)(ph + 1024 + d); for (int j = 0; j < 4; ++j) hz[j]  = bf2f(t[j]);
  t = *(const us4*)(ph + 2048 + d); for (int j = 0; j < 4; ++j) hnn[j] = bf2f(t[j]);
  float4 hv = *(const float4*)(h + (size_t)b * 1024 + d);
  float hvv[4] = {hv.x, hv.y, hv.z, hv.w};
  float ov[4]; us4 ob;
  #pragma unroll
  for (int j = 0; j < 4; ++j){
    float r = 1.f / (1.f + expf(-(ir[j] + hr[j])));
    float z = 1.f / (1.f + expf(-(iz[j] + hz[j])));
    float n = tanhf(in_[j] + r * hnn[j]);
    float o = (1.f - z) * n + z * hvv[j];
    ov[j] = o; ob[j] = f2bf(o);
  }
  float4 of; of.x = ov[0]; of.y = ov[1]; of.z = ov[2]; of.w = ov[3];
  *(float4*)(hn + (size_t)b * 1024 + d) = of;
  *(us4*)(hnbf + (size_t)b * 1024 + d) = ob;
}

// =========================== host ===========================
extern "C" void kernel_launch(void* const* d_in, const int* in_sizes, int n_in,
                              void* d_out, int out_size, void* d_ws, size_t ws_size,
                              hipStream_t stream) {
  (void)in_sizes; (void)n_in; (void)out_size;
  const float* query       = (const float*)d_in[0];
  const float* wm          = (const float*)d_in[1];
  const float* keys        = (const float*)d_in[2];
  const float* values      = (const float*)d_in[3];
  const float* last_access = (const float*)d_in[4];
  const float* importance  = (const float*)d_in[5];
  const float* consolid    = (const float*)d_in[6];
  const float* emo         = (const float*)d_in[7];
  const float* active      = (const float*)d_in[8];
  const float* in_proj_w   = (const float*)d_in[9];
  const float* in_proj_b   = (const float*)d_in[10];
  const float* out_w       = (const float*)d_in[11];
  const float* out_b       = (const float*)d_in[12];
  const float* msg_w1      = (const float*)d_in[13];
  const float* msg_b1      = (const float*)d_in[14];
  const float* msg_ln_g    = (const float*)d_in[15];
  const float* msg_ln_b    = (const float*)d_in[16];
  const float* msg_w2      = (const float*)d_in[17];
  const float* msg_b2      = (const float*)d_in[18];
  const float* gru_wih     = (const float*)d_in[19];
  const float* gru_whh     = (const float*)d_in[20];
  const float* gru_bih     = (const float*)d_in[21];
  const float* gru_bhh     = (const float*)d_in[22];
  const float* rsn_w1      = (const float*)d_in[23];
  const float* rsn_b1      = (const float*)d_in[24];
  const float* rsn_ln_g    = (const float*)d_in[25];
  const float* rsn_ln_b    = (const float*)d_in[26];
  const float* rsn_w2      = (const float*)d_in[27];
  const float* rsn_b2      = (const float*)d_in[28];
  float* out = (float*)d_out;

  // ---- workspace carve (lifetime-overlaid) ----
  size_t off = 0;
  char* base = (char*)d_ws;
  auto carve = [&](size_t bytes) -> char* {
    char* p = base + off;
    off += (bytes + 255) & ~(size_t)255;
    return p;
  };
  float* ascale = (float*)carve(4096*4);
  float* bbias  = (float*)carve(4096*4);
  float* bc_pre = (float*)carve(1024*4);
  float* bc_gi  = (float*)carve(3072*4);
  float* bc_ih  = (float*)carve(6144*4);
  unsigned short* wb_ihh  = (unsigned short*)carve((size_t)6144*1024*2);  // 12 MiB [inproj;gwhh]
  unsigned short* wb_rw1  = (unsigned short*)carve((size_t)1024*1024*2);
  unsigned short* wb_rw2  = (unsigned short*)carve((size_t)1024*1024*2);
  unsigned short* wb_Wab  = (unsigned short*)carve((size_t)1024*2048*2);
  unsigned short* wb_Wc   = (unsigned short*)carve((size_t)3072*1024*2);
  unsigned short* schema_bf = (unsigned short*)carve((size_t)8192*1024*2); // 16 MiB (later: preln/h1)
  float*          state_f   = (float*)carve((size_t)8192*1024*4);
  unsigned short* state_bf  = (unsigned short*)carve((size_t)8192*1024*2);
  unsigned short* qkvM      = (unsigned short*)carve((size_t)8192*3072*2); // 48 MiB
  unsigned short* qgh       = (unsigned short*)carve((size_t)8192*6144*2); // 96 MiB [qkv|gh]

  if (off > ws_size){
    k_diag<<<1, 1, 0, stream>>>(out, (float)(ws_size >> 20));
    return;
  }

  // prep-phase temporaries (qgh first half; dead before reasoner loop)
  unsigned short* tmp_w1bf  = qgh;
  unsigned short* tmp_outwT = qgh + (size_t)1024*2048;
  unsigned short* tmp_w2T   = tmp_outwT + (size_t)1024*1024;
  unsigned short* tmp_wihbf = tmp_w2T + (size_t)1024*1024;

  // retrieval-phase overlays (qkvM region; dead before reasoner writes qkvM)
  unsigned short* Qhi = qkvM;
  unsigned short* Qlo = Qhi + (size_t)8192*1024;
  unsigned short* Khi = Qlo + (size_t)8192*1024;
  unsigned short* Klo = Khi + (size_t)4096*1024;
  float* candV = (float*)(qgh + (size_t)8192*3072);          // 8 MiB (qgh second half)
  int*   candI = (int*)((char*)candV + (size_t)8192*256*4);  // 8 MiB

  unsigned short* preln_h1 = schema_bf;   // reused per step (schema dead after qkvM GEMM)

  // ---- weight prep ----
  auto cast = [&](const float* src, unsigned short* dst, int n){
    k_cast_bf16<<<1024, 256, 0, stream>>>(src, dst, n / 4);
  };
  cast(in_proj_w, wb_ihh,                     3072*1024);
  cast(gru_whh,   wb_ihh + (size_t)3072*1024, 3072*1024);
  cast(rsn_w1,    wb_rw1,    1024*1024);
  cast(rsn_w2,    wb_rw2,    1024*1024);
  cast(msg_w1,    tmp_w1bf,  1024*2048);
  cast(gru_wih,   tmp_wihbf, 3072*1024);
  hipMemcpyAsync(bc_ih,        in_proj_b, 3072*4, hipMemcpyDeviceToDevice, stream);
  hipMemcpyAsync(bc_ih + 3072, gru_bhh,   3072*4, hipMemcpyDeviceToDevice, stream);
  k_tcast<<<dim3(32, 32), 256, 0, stream>>>(out_w,  tmp_outwT, 1024, 1024);
  k_tcast<<<dim3(32, 32), 256, 0, stream>>>(msg_w2, tmp_w2T,   1024, 1024);
  k_bias_pre<<<256, 256, 0, stream>>>(msg_w1, out_b, msg_b1, bc_pre);
  k_bias_gi<<<768, 256, 0, stream>>>(gru_wih, msg_b2, gru_bih, bc_gi);
  k_gemm<1><<<dim3(8, 8), 256, 0, stream>>>(tmp_w1bf,        tmp_outwT, nullptr, wb_Wab,        1024, 1024, 1024, 2048, 2048);
  k_gemm<1><<<dim3(8, 8), 256, 0, stream>>>(tmp_w1bf + 1024, tmp_outwT, nullptr, wb_Wab + 1024, 1024, 1024, 1024, 2048, 2048);
  k_gemm<1><<<dim3(24, 8), 256, 0, stream>>>(tmp_wihbf, tmp_w2T, nullptr, wb_Wc, 3072, 1024, 1024, 1024, 1024);

  // ---- retrieval (fused norm+split producers) ----
  k_splitq<<<8192, 256, 0, stream>>>(query, Qhi, Qlo);
  k_splitk<<<4096, 256, 0, stream>>>(keys, last_access, importance, consolid, emo, active,
                                     ascale, bbias, Khi, Klo);
  k_scores_mfma<<<dim3(64, 32), 256, 0, stream>>>(Qhi, Qlo, Khi, Klo, ascale, bbias, candV, candI);
  k_topk_merge<<<8192, 256, 0, stream>>>(candV, candI, values, schema_bf);

  // ---- reasoner ----
  k_initstate<<<8192, 256, 0, stream>>>(wm, state_f, state_bf);
  // schema token qkv (loop-invariant) — uses first 3072 rows of wb_ihh (= inproj)
  k_gemm8p<1><<<dim3(32, 12), 512, 0, stream>>>(schema_bf, wb_ihh, bc_ih, qkvM, 8192, 3072, 1024, 1024, 3072);
  for (int s = 0; s < 3; ++s){
    // merged: [qkv | gh] = state @ [inproj ; gwhh]^T  — 768 blocks = exactly 3 CU-waves
    k_gemm8p<1><<<dim3(32, 24), 512, 0, stream>>>(state_bf, wb_ihh, bc_ih, qgh, 8192, 6144, 1024, 1024, 6144);
    k_attn<<<8192, 256, 0, stream>>>(qgh, qkvM);
    // preln(bf16) = catt(qgh cols 0..2047) @ [Wa|Wb]^T + bc_pre  -> schema region
    k_gemm<1><<<dim3(64, 8), 256, 0, stream>>>(qgh, wb_Wab, bc_pre, preln_h1, 8192, 1024, 2048, 6144, 1024);
    k_ln_relu<1><<<8192, 256, 0, stream>>>(preln_h1, msg_ln_g, msg_ln_b, preln_h1); // in-place
    // gi = h1 @ Wc^T + bc_gi  -> qgh cols 0..3071 (qkv region dead after preln GEMM)
    k_gemm8p<1><<<dim3(32, 12), 512, 0, stream>>>(preln_h1, wb_Wc, bc_gi, qgh, 8192, 3072, 1024, 1024, 6144);
    k_gru<<<8192, 256, 0, stream>>>(qgh, state_f, state_f, state_bf);
  }
  // ---- head (qgh fully dead) ----
  float* hpre = (float*)qgh;                                   // 32 MiB
  unsigned short* hh1 = qgh + (size_t)8192*3072;               // 16 MiB, disjoint
  k_gemm<0><<<dim3(64, 8), 256, 0, stream>>>(state_bf, wb_rw1, rsn_b1, hpre, 8192, 1024, 1024, 1024, 1024);
  k_ln_relu<0><<<8192, 256, 0, stream>>>(hpre, rsn_ln_g, rsn_ln_b, hh1);
  k_gemm<0><<<dim3(64, 8), 256, 0, stream>>>(hh1, wb_rw2, rsn_b2, out, 8192, 1024, 1024, 1024, 1024);
}